// Round 13
// baseline (112.746 us; speedup 1.0000x reference)
//
#include <hip/hip_runtime.h>
#include <hip/hip_bf16.h>
#include <hip/hip_fp16.h>

typedef __attribute__((ext_vector_type(4))) float f32x4;
typedef __attribute__((ext_vector_type(8))) short bf16x8;
typedef __attribute__((ext_vector_type(4))) short bf16x4;
typedef unsigned short u16;
typedef unsigned char u8;

__device__ __forceinline__ short fbf(float f){   // f32 -> bf16 (RNE)
  __hip_bfloat16 h = __float2bfloat16(f);
  return *reinterpret_cast<short*>(&h);
}
__device__ __forceinline__ float bf2f(short s){
  return __uint_as_float(((unsigned)(unsigned short)s) << 16);
}
// f32 -> e5m2 (top byte of f16, RNE twice) -- storage-only format for V
__device__ __forceinline__ unsigned f2e5(float v){
  __half h = __float2half(v);
  unsigned hu = (unsigned)*reinterpret_cast<unsigned short*>(&h);
  hu = hu + 0x7Fu + ((hu >> 8) & 1u);
  return (hu >> 8) & 0xFFu;
}
__device__ __forceinline__ float e52f(unsigned b){  // exact
  unsigned short hb = (unsigned short)(b << 8);
  __half h = *reinterpret_cast<__half*>(&hb);
  return __half2float(h);
}

#define LOG2E 1.4426950408889634f

// ---------------------------------------------------------------------------
// K0: repack f32 weights into bf16 MFMA fragment order + expand relative
// bias into MFMA C-fragment layout for S^T = K·Q^T (row=k_token, col=q_token),
// pre-scaled by log2(e) for exp2-domain softmax.
// Fragment (kk, nt, lane, j) holds W[k = kk*32 + (lane>>4)*8 + j][nt*16 + (lane&15)].
// ---------------------------------------------------------------------------
__global__ void repack_kernel(const float* __restrict__ qkv_w, const float* __restrict__ proj_w,
                              const float* __restrict__ w1, const float* __restrict__ w2,
                              const float* __restrict__ tbl,
                              u16* __restrict__ rq, u16* __restrict__ rp,
                              u16* __restrict__ r1, u16* __restrict__ r2,
                              float* __restrict__ be){
  const int i = blockIdx.x * 256 + threadIdx.x;          // 0 .. 65535
  const int j = i & 7, lane = (i >> 3) & 63, f = i >> 9;
  const int kr = (lane >> 4) * 8 + j;                    // k within 32-chunk
  const int c16 = lane & 15;
  if (i < 49152){ int nt = f % 24, kk = f / 24; rq[i] = (u16)fbf(qkv_w[(kk*32 + kr)*384 + nt*16 + c16]); }
  if (i < 16384){ int nt = f & 7,  kk = f >> 3; rp[i] = (u16)fbf(proj_w[(kk*32 + kr)*128 + nt*16 + c16]); }
  if (i < 65536){ int nt = f & 31, kk = f >> 5; r1[i] = (u16)fbf(w1[(kk*32 + kr)*512 + nt*16 + c16]); }
  if (i < 65536){ int nt = f & 7,  kk = f >> 3; r2[i] = (u16)fbf(w2[(kk*32 + kr)*128 + nt*16 + c16]); }
  if (i < 16384){
    int rg = i & 3, ln = (i >> 2) & 63, g = i >> 8;
    int nt = g & 3, mt = (g >> 2) & 3, h = g >> 4;
    int row = mt*16 + (ln >> 4)*4 + rg;   // k_token (C row)
    int col = nt*16 + (ln & 15);          // q_token (C col)
    int rel = ((col >> 3) - (row >> 3) + 7) * 15 + ((col & 7) - (row & 7) + 7);
    be[i] = tbl[rel*4 + h] * LOG2E;
  }
}

// ---------------------------------------------------------------------------
// K1: fully fused Swin block, one workgroup per 64-token window.
// 512 threads = 8 waves: wave = (head = wid8&3, half = wid8>>2); each wave
// handles its head's work on its half of the token tiles. Same 40 KB LDS as
// the 4-wave version -> fat blocks double waves/CU at the observed ~3-block
// residency cap. Barrier/overlay structure identical to R12 (audited: the
// only new cross-wave edge, V write-half vs read-full, sits behind B3).
// LDS map (u16): A [0,8192) | B [8192,16384) | C [16384,20480)
//   A: sLN -> sQ -> sP(h0,h1) -> sO -> sH
//   B: sK -> sP(h2,h3) -> stg (msa bf16)
//   C: sVe5 (V^T [128][64] e5m2) -> sG ([64 tok][64 hid] bf16)
// ---------------------------------------------------------------------------
__global__ __launch_bounds__(512, 2)
void block_kernel(const float* __restrict__ x,
                  const float* __restrict__ qkv_b, const float* __restrict__ proj_b,
                  const float* __restrict__ ln1_g, const float* __restrict__ ln1_b,
                  const float* __restrict__ ln2_g, const float* __restrict__ ln2_b,
                  const u16* __restrict__ rep_qkv, const u16* __restrict__ rep_proj,
                  const u16* __restrict__ rep_w1, const u16* __restrict__ rep_w2,
                  const float* __restrict__ mlp_b1, const float* __restrict__ mlp_b2,
                  const float* __restrict__ bias_exp,
                  float* __restrict__ out){
  __shared__ __align__(16) u16 smem[20480];   // 40 KB
  u16* sLN = smem;
  u16* sQ  = smem;
  u16* sK  = smem + 8192;
  u16* sP  = smem;                    // per-head [64 q][64 k] at head*4096 u16
  u16* sO  = smem;
  u16* stg = smem + 8192;
  u16* sH  = smem;
  u16* sG  = smem + 16384;
  u8*  sVe5 = (u8*)(smem + 16384);

  const int tid = threadIdx.x, lane = tid & 63, wid8 = tid >> 6;
  const int head = wid8 & 3, half = wid8 >> 2, tb = half * 2;
  const int wdw = blockIdx.x;
  const int bb = wdw >> 6, ihb = (wdw >> 3) & 7, iwb = wdw & 7;
  const float* xb = x + (size_t)bb * 4096 * 128;
  float* ob = out + (size_t)bb * 4096 * 128;
  const f32x4 z4 = {0.f, 0.f, 0.f, 0.f};
  const int rb = tid >> 4, cb = tid & 15, c0g = cb * 8;   // rb 0..31
  const int r15 = lane & 15, kg = lane >> 4;

  // ---- P1: load window + LN1 -> sLN (coalesced; 2 rows/thread) ----
  {
    float g8[8], b8[8];
    *(f32x4*)&g8[0] = *(const f32x4*)(ln1_g + c0g);
    *(f32x4*)&g8[4] = *(const f32x4*)(ln1_g + c0g + 4);
    *(f32x4*)&b8[0] = *(const f32x4*)(ln1_b + c0g);
    *(f32x4*)&b8[4] = *(const f32x4*)(ln1_b + c0g + 4);
    #pragma unroll
    for (int it = 0; it < 2; ++it){
      const int r = it * 32 + rb;
      const int pix = ((r >> 3) * 8 + ihb) * 64 + (r & 7) * 8 + iwb;
      float fl[8];
      *(f32x4*)&fl[0] = *(const f32x4*)(xb + (size_t)pix * 128 + c0g);
      *(f32x4*)&fl[4] = *(const f32x4*)(xb + (size_t)pix * 128 + c0g + 4);
      float s = 0.f, sq = 0.f;
      #pragma unroll
      for (int j = 0; j < 8; ++j){ s += fl[j]; sq += fl[j]*fl[j]; }
      #pragma unroll
      for (int m = 1; m < 16; m <<= 1){ s += __shfl_xor(s, m); sq += __shfl_xor(sq, m); }
      const float mean = s * (1.f/128.f);
      const float rs = __builtin_amdgcn_rsqf(sq * (1.f/128.f) - mean*mean + 1e-5f);
      bf16x8 o;
      #pragma unroll
      for (int j = 0; j < 8; ++j) o[j] = fbf((fl[j]-mean)*rs*g8[j] + b8[j]);
      *(bf16x8*)&sLN[r*128 + (c0g ^ ((r & 7) << 3))] = o;
    }
  }
  __syncthreads();   // B1

  // ---- P2: QKV (wave = head x token-half) ----
  {
    f32x4 aqk[4][2];   // [chtile Q0,Q1,K0,K1][token tile (half)]
    f32x4 av[2][2];    // [token tile (half)][d tile]
    #pragma unroll
    for (int ct = 0; ct < 4; ++ct){
      const f32x4 bq = *(const f32x4*)(qkv_b + head*96 + ct*16 + kg*4);
      #pragma unroll
      for (int t2 = 0; t2 < 2; ++t2) aqk[ct][t2] = bq;
    }
    #pragma unroll
    for (int nt = 0; nt < 2; ++nt){
      const float bv = qkv_b[head*96 + 64 + nt*16 + r15];
      const f32x4 bv4 = {bv, bv, bv, bv};
      #pragma unroll
      for (int t2 = 0; t2 < 2; ++t2) av[t2][nt] = bv4;
    }
    #pragma unroll
    for (int kk = 0; kk < 4; ++kk){
      bf16x8 L[2], aW[4], bWv[2];
      const int c0 = kk*32 + kg*8;
      #pragma unroll
      for (int t2 = 0; t2 < 2; ++t2){
        const int row = (tb + t2)*16 + r15;
        L[t2] = *(const bf16x8*)&sLN[row*128 + (c0 ^ ((row & 7) << 3))];
      }
      #pragma unroll
      for (int ct = 0; ct < 4; ++ct)
        aW[ct] = *(const bf16x8*)(rep_qkv + (size_t)((kk*24 + head*6 + ct)*64 + lane)*8);
      #pragma unroll
      for (int nt = 0; nt < 2; ++nt)
        bWv[nt] = *(const bf16x8*)(rep_qkv + (size_t)((kk*24 + head*6 + 4 + nt)*64 + lane)*8);
      #pragma unroll
      for (int ct = 0; ct < 4; ++ct)
        #pragma unroll
        for (int t2 = 0; t2 < 2; ++t2)
          aqk[ct][t2] = __builtin_amdgcn_mfma_f32_16x16x32_bf16(aW[ct], L[t2], aqk[ct][t2], 0, 0, 0);
      #pragma unroll
      for (int t2 = 0; t2 < 2; ++t2)
        #pragma unroll
        for (int nt = 0; nt < 2; ++nt)
          av[t2][nt] = __builtin_amdgcn_mfma_f32_16x16x32_bf16(L[t2], bWv[nt], av[t2][nt], 0, 0, 0);
    }
    __syncthreads();   // B2: sLN dead; sQ may overlay
    // Q (pre-scaled by 1/sqrt(HD)*log2e), K stores: own-half rows
    #pragma unroll
    for (int ct = 0; ct < 4; ++ct){
      u16* dst = (ct < 2) ? sQ : sK;
      const float scl = (ct < 2) ? 0.2550348296f : 1.0f;
      const int colu = head*32 + (ct & 1)*16 + kg*4;
      #pragma unroll
      for (int t2 = 0; t2 < 2; ++t2){
        const int row = (tb + t2)*16 + r15;
        bf16x4 pk;
        #pragma unroll
        for (int rg = 0; rg < 4; ++rg) pk[rg] = fbf(aqk[ct][t2][rg] * scl);
        *(bf16x4*)&dst[row*128 + (colu ^ ((row & 7) << 3))] = pk;
      }
    }
    // V -> e5m2 V^T: own-half token cols (cross-half reads protected by B3)
    #pragma unroll
    for (int nt = 0; nt < 2; ++nt){
      const int row = head*32 + nt*16 + r15;       // d_all
      #pragma unroll
      for (int t2 = 0; t2 < 2; ++t2){
        const int colu = (tb + t2)*16 + kg*4;      // token (byte)
        unsigned pk = f2e5(av[t2][nt][0]) | (f2e5(av[t2][nt][1]) << 8)
                    | (f2e5(av[t2][nt][2]) << 16) | (f2e5(av[t2][nt][3]) << 24);
        *(unsigned*)(sVe5 + row*64 + (colu ^ ((row & 7) << 3))) = pk;
      }
    }
  }
  __syncthreads();   // B3

  // ---- P3: S^T = K·Q^T + bias (C-input), softmax over k (exp2, no-max) ----
  f32x4 s4[4][2];   // [k tile][q tile (half)]
  {
    bf16x8 aK[4], bQ[2];
    #pragma unroll
    for (int t = 0; t < 4; ++t){
      const int row = t*16 + r15;
      aK[t] = *(const bf16x8*)&sK[row*128 + ((head*32 + kg*8) ^ ((row & 7) << 3))];
    }
    #pragma unroll
    for (int q2 = 0; q2 < 2; ++q2){
      const int row = (tb + q2)*16 + r15;
      bQ[q2] = *(const bf16x8*)&sQ[row*128 + ((head*32 + kg*8) ^ ((row & 7) << 3))];
    }
    #pragma unroll
    for (int mtk = 0; mtk < 4; ++mtk)
      #pragma unroll
      for (int q2 = 0; q2 < 2; ++q2){
        const f32x4 cb4 = *(const f32x4*)(bias_exp + (size_t)(((head*4 + mtk)*4 + tb + q2)*64 + lane)*4);
        s4[mtk][q2] = __builtin_amdgcn_mfma_f32_16x16x32_bf16(aK[mtk], bQ[q2], cb4, 0, 0, 0);
      }
  }
  #pragma unroll
  for (int q2 = 0; q2 < 2; ++q2){
    float sum = 0.f;
    #pragma unroll
    for (int mtk = 0; mtk < 4; ++mtk)
      #pragma unroll
      for (int rg = 0; rg < 4; ++rg){
        const float e = __builtin_amdgcn_exp2f(s4[mtk][q2][rg]);
        s4[mtk][q2][rg] = e; sum += e;
      }
    sum += __shfl_xor(sum, 16);
    sum += __shfl_xor(sum, 32);
    const float inv = __builtin_amdgcn_rcpf(sum);
    #pragma unroll
    for (int mtk = 0; mtk < 4; ++mtk)
      #pragma unroll
      for (int rg = 0; rg < 4; ++rg) s4[mtk][q2][rg] *= inv;
  }
  __syncthreads();   // B4: Q/K dead; sP overlays A+B
  #pragma unroll
  for (int q2 = 0; q2 < 2; ++q2){
    const int row = (tb + q2)*16 + r15;           // q (own-half)
    #pragma unroll
    for (int mtk = 0; mtk < 4; ++mtk){
      const int colu = mtk*16 + kg*4;             // k local
      bf16x4 pk;
      #pragma unroll
      for (int rg = 0; rg < 4; ++rg) pk[rg] = fbf(s4[mtk][q2][rg]);
      *(bf16x4*)&sP[head*4096 + row*64 + (colu ^ ((row & 7) << 3))] = pk;
    }
  }
  // no barrier: this wave's P4 reads only its own P rows; V reads are pre-B3

  // ---- P4: O^T = V^T·P^T (V decoded e5m2->bf16) -> sO[tok][ch] ----
  {
    f32x4 o4[2][2];   // [d tile][q tile (half)]
    #pragma unroll
    for (int dt = 0; dt < 2; ++dt)
      #pragma unroll
      for (int q2 = 0; q2 < 2; ++q2) o4[dt][q2] = z4;
    #pragma unroll
    for (int ks = 0; ks < 2; ++ks){
      bf16x8 aV[2], bP[2];
      #pragma unroll
      for (int dt = 0; dt < 2; ++dt){
        const int rowd = head*32 + dt*16 + r15;
        const u8* pv = sVe5 + rowd*64 + ((ks*32 + kg*8) ^ ((rowd & 7) << 3));
        const unsigned w0 = *(const unsigned*)pv;
        const unsigned w1 = *(const unsigned*)(pv + 4);
        bf16x8 a;
        #pragma unroll
        for (int j = 0; j < 4; ++j){
          a[j]   = fbf(e52f((w0 >> (8*j)) & 0xFFu));
          a[4+j] = fbf(e52f((w1 >> (8*j)) & 0xFFu));
        }
        aV[dt] = a;
      }
      #pragma unroll
      for (int q2 = 0; q2 < 2; ++q2){
        const int rowq = (tb + q2)*16 + r15;
        bP[q2] = *(const bf16x8*)&sP[head*4096 + rowq*64 + ((ks*32 + kg*8) ^ ((rowq & 7) << 3))];
      }
      #pragma unroll
      for (int dt = 0; dt < 2; ++dt)
        #pragma unroll
        for (int q2 = 0; q2 < 2; ++q2)
          o4[dt][q2] = __builtin_amdgcn_mfma_f32_16x16x32_bf16(aV[dt], bP[q2], o4[dt][q2], 0, 0, 0);
    }
    __syncthreads();   // B6: P,V dead; sO overlays A
    #pragma unroll
    for (int dt = 0; dt < 2; ++dt){
      const int dbase = head*32 + dt*16 + kg*4;
      #pragma unroll
      for (int q2 = 0; q2 < 2; ++q2){
        const int q = (tb + q2)*16 + r15;
        bf16x4 pk;
        #pragma unroll
        for (int rg = 0; rg < 4; ++rg) pk[rg] = fbf(o4[dt][q2][rg]);
        *(bf16x4*)&sO[q*128 + (dbase ^ ((q & 7) << 3))] = pk;
      }
    }
  }
  __syncthreads();   // B7: O complete

  // ---- P5: proj^T; msa = x + proj -> stg (bf16, B) ----
  {
    f32x4 xv[2][2];
    #pragma unroll
    for (int ot = 0; ot < 2; ++ot){
      const int cbase = (head*2 + ot)*16 + kg*4;
      #pragma unroll
      for (int t2 = 0; t2 < 2; ++t2){
        const int tok = (tb + t2)*16 + r15;
        const int pix = ((tok >> 3) * 8 + ihb) * 64 + (tok & 7) * 8 + iwb;
        xv[ot][t2] = *(const f32x4*)(xb + (size_t)pix * 128 + cbase);
      }
    }
    f32x4 po[2][2];   // [out-ch tile][token tile (half)]
    #pragma unroll
    for (int ot = 0; ot < 2; ++ot){
      const f32x4 pb4 = *(const f32x4*)(proj_b + (head*2 + ot)*16 + kg*4);
      #pragma unroll
      for (int t2 = 0; t2 < 2; ++t2) po[ot][t2] = pb4;
    }
    #pragma unroll
    for (int kk = 0; kk < 4; ++kk){
      bf16x8 aWp[2], bO[2];
      #pragma unroll
      for (int ot = 0; ot < 2; ++ot)
        aWp[ot] = *(const bf16x8*)(rep_proj + (size_t)((kk*8 + head*2 + ot)*64 + lane)*8);
      #pragma unroll
      for (int t2 = 0; t2 < 2; ++t2){
        const int row = (tb + t2)*16 + r15;
        bO[t2] = *(const bf16x8*)&sO[row*128 + ((kk*32 + kg*8) ^ ((row & 7) << 3))];
      }
      #pragma unroll
      for (int ot = 0; ot < 2; ++ot)
        #pragma unroll
        for (int t2 = 0; t2 < 2; ++t2)
          po[ot][t2] = __builtin_amdgcn_mfma_f32_16x16x32_bf16(aWp[ot], bO[t2], po[ot][t2], 0, 0, 0);
    }
    #pragma unroll
    for (int ot = 0; ot < 2; ++ot){
      const int cbase = (head*2 + ot)*16 + kg*4;
      #pragma unroll
      for (int t2 = 0; t2 < 2; ++t2){
        const int tok = (tb + t2)*16 + r15;
        bf16x4 pk;
        #pragma unroll
        for (int rg = 0; rg < 4; ++rg) pk[rg] = fbf(po[ot][t2][rg] + xv[ot][t2][rg]);
        *(bf16x4*)&stg[tok*128 + (cbase ^ ((tok & 7) << 3))] = pk;
      }
    }
  }
  __syncthreads();   // B8: msa(stg) ready; sO reads done

  // ---- P6: LN2(stg) -> sH (A, overlays sO); 2 rows/thread ----
  {
    float g8[8], b8[8];
    *(f32x4*)&g8[0] = *(const f32x4*)(ln2_g + c0g);
    *(f32x4*)&g8[4] = *(const f32x4*)(ln2_g + c0g + 4);
    *(f32x4*)&b8[0] = *(const f32x4*)(ln2_b + c0g);
    *(f32x4*)&b8[4] = *(const f32x4*)(ln2_b + c0g + 4);
    #pragma unroll
    for (int it = 0; it < 2; ++it){
      const int r = it * 32 + rb;
      bf16x8 m8 = *(const bf16x8*)&stg[r*128 + (c0g ^ ((r & 7) << 3))];
      float fl[8];
      #pragma unroll
      for (int j = 0; j < 8; ++j) fl[j] = bf2f(m8[j]);
      float s = 0.f, sq = 0.f;
      #pragma unroll
      for (int j = 0; j < 8; ++j){ s += fl[j]; sq += fl[j]*fl[j]; }
      #pragma unroll
      for (int m = 1; m < 16; m <<= 1){ s += __shfl_xor(s, m); sq += __shfl_xor(sq, m); }
      const float mean = s * (1.f/128.f);
      const float rs = __builtin_amdgcn_rsqf(sq * (1.f/128.f) - mean*mean + 1e-5f);
      bf16x8 o;
      #pragma unroll
      for (int j = 0; j < 8; ++j) o[j] = fbf((fl[j]-mean)*rs*g8[j] + b8[j]);
      *(bf16x8*)&sH[r*128 + (c0g ^ ((r & 7) << 3))] = o;
    }
  }
  __syncthreads();   // B9

  // ---- P7: MLP transposed, 8 chunks of 64 hidden (sG 8KB in C) ----
  f32x4 accO[2][2];   // [out-ch tile][token tile (half)]
  #pragma unroll
  for (int ot = 0; ot < 2; ++ot){
    const f32x4 b2v = *(const f32x4*)(mlp_b2 + (head*2 + ot)*16 + kg*4);
    #pragma unroll
    for (int t2 = 0; t2 < 2; ++t2) accO[ot][t2] = b2v;
  }
  #pragma unroll
  for (int c = 0; c < 8; ++c){
    f32x4 t4[2];      // [token tile (half)]; wave owns hidden 16-group c*4+head
    {
      const f32x4 b1v = *(const f32x4*)(mlp_b1 + (c*4 + head)*16 + kg*4);
      #pragma unroll
      for (int t2 = 0; t2 < 2; ++t2) t4[t2] = b1v;
    }
    #pragma unroll
    for (int kk = 0; kk < 4; ++kk){
      const int c0 = kk*32 + kg*8;
      bf16x8 aW = *(const bf16x8*)(rep_w1 + (size_t)((kk*32 + c*4 + head)*64 + lane)*8);
      bf16x8 bL[2];
      #pragma unroll
      for (int t2 = 0; t2 < 2; ++t2){
        const int row = (tb + t2)*16 + r15;
        bL[t2] = *(const bf16x8*)&sH[row*128 + (c0 ^ ((row & 7) << 3))];
      }
      #pragma unroll
      for (int t2 = 0; t2 < 2; ++t2)
        t4[t2] = __builtin_amdgcn_mfma_f32_16x16x32_bf16(aW, bL[t2], t4[t2], 0, 0, 0);
    }
    // sigmoid-GELU (exp2 domain)
    bf16x4 gp[2];
    #pragma unroll
    for (int t2 = 0; t2 < 2; ++t2){
      #pragma unroll
      for (int rg = 0; rg < 4; ++rg){
        const float v = t4[t2][rg];
        const float e = __builtin_amdgcn_exp2f(-2.4554669f * v);
        gp[t2][rg] = fbf(v * __builtin_amdgcn_rcpf(1.f + e));
      }
    }
    __syncthreads();   // prior chunk's sG reads complete (c=0: V reads pre-B6)
    {
      const int colu = head*16 + kg*4;            // hidden local [0,64)
      #pragma unroll
      for (int t2 = 0; t2 < 2; ++t2){
        const int row = (tb + t2)*16 + r15;
        *(bf16x4*)&sG[row*64 + (colu ^ ((row & 7) << 3))] = gp[t2];
      }
    }
    __syncthreads();   // sG ready
    #pragma unroll
    for (int kk2 = 0; kk2 < 2; ++kk2){
      bf16x8 aW2[2], bG[2];
      const int c0 = kk2*32 + kg*8;
      #pragma unroll
      for (int ot = 0; ot < 2; ++ot)
        aW2[ot] = *(const bf16x8*)(rep_w2 + (size_t)(((c*2 + kk2)*8 + head*2 + ot)*64 + lane)*8);
      #pragma unroll
      for (int t2 = 0; t2 < 2; ++t2){
        const int row = (tb + t2)*16 + r15;
        bG[t2] = *(const bf16x8*)&sG[row*64 + (c0 ^ ((row & 7) << 3))];
      }
      #pragma unroll
      for (int ot = 0; ot < 2; ++ot)
        #pragma unroll
        for (int t2 = 0; t2 < 2; ++t2)
          accO[ot][t2] = __builtin_amdgcn_mfma_f32_16x16x32_bf16(aW2[ot], bG[t2], accO[ot][t2], 0, 0, 0);
    }
  }

  // ---- P8: out = msa(stg bf16) + mlp, scattered to image layout ----
  #pragma unroll
  for (int ot = 0; ot < 2; ++ot){
    const int cbase = (head*2 + ot)*16 + kg*4;
    #pragma unroll
    for (int t2 = 0; t2 < 2; ++t2){
      const int tok = (tb + t2)*16 + r15;
      const int pix = ((tok >> 3) * 8 + ihb) * 64 + (tok & 7) * 8 + iwb;
      bf16x4 m4 = *(const bf16x4*)&stg[tok*128 + (cbase ^ ((tok & 7) << 3))];
      f32x4 o;
      #pragma unroll
      for (int rg = 0; rg < 4; ++rg) o[rg] = bf2f(m4[rg]) + accO[ot][t2][rg];
      *(f32x4*)(ob + (size_t)pix * 128 + cbase) = o;
    }
  }
}

// ---------------------------------------------------------------------------
// ws layout (bytes): rq 0..98304 | rp ..131072 | r1 ..262144 | r2 ..393216 |
// be ..458752.
// ---------------------------------------------------------------------------
extern "C" void kernel_launch(void* const* d_in, const int* in_sizes, int n_in,
                              void* d_out, int out_size, void* d_ws, size_t ws_size,
                              hipStream_t stream){
  (void)in_sizes; (void)n_in; (void)out_size; (void)ws_size;
  const float* x      = (const float*)d_in[0];
  const float* qkv_w  = (const float*)d_in[1];
  const float* qkv_b  = (const float*)d_in[2];
  const float* proj_w = (const float*)d_in[3];
  const float* proj_b = (const float*)d_in[4];
  const float* tbl    = (const float*)d_in[5];
  const float* ln1_g  = (const float*)d_in[6];
  const float* ln1_b  = (const float*)d_in[7];
  const float* ln2_g  = (const float*)d_in[8];
  const float* ln2_b  = (const float*)d_in[9];
  const float* w1     = (const float*)d_in[10];
  const float* b1     = (const float*)d_in[11];
  const float* w2     = (const float*)d_in[12];
  const float* b2     = (const float*)d_in[13];

  char* ws = (char*)d_ws;
  u16*   rq  = (u16*)ws;
  u16*   rp  = (u16*)(ws + 98304);
  u16*   r1  = (u16*)(ws + 131072);
  u16*   r2  = (u16*)(ws + 262144);
  float* be  = (float*)(ws + 393216);

  hipLaunchKernelGGL(repack_kernel, dim3(256), dim3(256), 0, stream,
                     qkv_w, proj_w, w1, w2, tbl, rq, rp, r1, r2, be);
  hipLaunchKernelGGL(block_kernel, dim3(2048), dim3(512), 0, stream,
                     x, qkv_b, proj_b, ln1_g, ln1_b, ln2_g, ln2_b,
                     rq, rp, r1, r2, b1, b2, be, (float*)d_out);
}

// Round 14
// 102.213 us; speedup vs baseline: 1.1030x; 1.1030x over previous
//
#include <hip/hip_runtime.h>
#include <hip/hip_bf16.h>
#include <hip/hip_fp16.h>

typedef __attribute__((ext_vector_type(4))) float f32x4;
typedef __attribute__((ext_vector_type(8))) short bf16x8;
typedef __attribute__((ext_vector_type(4))) short bf16x4;
typedef unsigned short u16;
typedef unsigned char u8;

__device__ __forceinline__ short fbf(float f){   // f32 -> bf16 (RNE)
  __hip_bfloat16 h = __float2bfloat16(f);
  return *reinterpret_cast<short*>(&h);
}
__device__ __forceinline__ float bf2f(short s){
  return __uint_as_float(((unsigned)(unsigned short)s) << 16);
}
// f32 -> e5m2 (top byte of f16, RNE twice) -- storage-only format for V
__device__ __forceinline__ unsigned f2e5(float v){
  __half h = __float2half(v);
  unsigned hu = (unsigned)*reinterpret_cast<unsigned short*>(&h);
  hu = hu + 0x7Fu + ((hu >> 8) & 1u);
  return (hu >> 8) & 0xFFu;
}
__device__ __forceinline__ float e52f(unsigned b){  // exact
  unsigned short hb = (unsigned short)(b << 8);
  __half h = *reinterpret_cast<__half*>(&hb);
  return __half2float(h);
}

#define LOG2E 1.4426950408889634f

// ---------------------------------------------------------------------------
// K0: repack f32 weights into bf16 MFMA fragment order + expand relative
// bias into MFMA C-fragment layout for S^T = K·Q^T (row=k_token, col=q_token),
// pre-scaled by log2(e) for exp2-domain softmax.
// Fragment (kk, nt, lane, j) holds W[k = kk*32 + (lane>>4)*8 + j][nt*16 + (lane&15)].
// ---------------------------------------------------------------------------
__global__ void repack_kernel(const float* __restrict__ qkv_w, const float* __restrict__ proj_w,
                              const float* __restrict__ w1, const float* __restrict__ w2,
                              const float* __restrict__ tbl,
                              u16* __restrict__ rq, u16* __restrict__ rp,
                              u16* __restrict__ r1, u16* __restrict__ r2,
                              float* __restrict__ be){
  const int i = blockIdx.x * 256 + threadIdx.x;          // 0 .. 65535
  const int j = i & 7, lane = (i >> 3) & 63, f = i >> 9;
  const int kr = (lane >> 4) * 8 + j;                    // k within 32-chunk
  const int c16 = lane & 15;
  if (i < 49152){ int nt = f % 24, kk = f / 24; rq[i] = (u16)fbf(qkv_w[(kk*32 + kr)*384 + nt*16 + c16]); }
  if (i < 16384){ int nt = f & 7,  kk = f >> 3; rp[i] = (u16)fbf(proj_w[(kk*32 + kr)*128 + nt*16 + c16]); }
  if (i < 65536){ int nt = f & 31, kk = f >> 5; r1[i] = (u16)fbf(w1[(kk*32 + kr)*512 + nt*16 + c16]); }
  if (i < 65536){ int nt = f & 7,  kk = f >> 3; r2[i] = (u16)fbf(w2[(kk*32 + kr)*128 + nt*16 + c16]); }
  if (i < 16384){
    int rg = i & 3, ln = (i >> 2) & 63, g = i >> 8;
    int nt = g & 3, mt = (g >> 2) & 3, h = g >> 4;
    int row = mt*16 + (ln >> 4)*4 + rg;   // k_token (C row)
    int col = nt*16 + (ln & 15);          // q_token (C col)
    int rel = ((col >> 3) - (row >> 3) + 7) * 15 + ((col & 7) - (row & 7) + 7);
    be[i] = tbl[rel*4 + h] * LOG2E;
  }
}

// ---------------------------------------------------------------------------
// K1: fully fused Swin block, one workgroup per 64-token window.
// 256 threads (4 waves, wave == head for attn). LDS 40 KB.
// V stored e5m2 (storage only; MFMA stays bf16). MLP runs 8 chunks of 64
// hidden, software-pipelined: GEMM1(c+1) issues between the sG-ready barrier
// and GEMM2(c) so each inter-barrier window carries 12 MFMAs.
// LDS map (u16 regions): A [0,8192) | B [8192,16384) | C [16384,20480) (8KB)
//   A: sLN -> sQ -> sP(h0,h1) -> sO -> sH
//   B: sK -> sP(h2,h3) -> stg (msa bf16)
//   C: sVe5 (V^T [128][64] e5m2) -> sG ([64 tok][64 hid] bf16)
// ---------------------------------------------------------------------------
__global__ __launch_bounds__(256, 3)
void block_kernel(const float* __restrict__ x,
                  const float* __restrict__ qkv_b, const float* __restrict__ proj_b,
                  const float* __restrict__ ln1_g, const float* __restrict__ ln1_b,
                  const float* __restrict__ ln2_g, const float* __restrict__ ln2_b,
                  const u16* __restrict__ rep_qkv, const u16* __restrict__ rep_proj,
                  const u16* __restrict__ rep_w1, const u16* __restrict__ rep_w2,
                  const float* __restrict__ mlp_b1, const float* __restrict__ mlp_b2,
                  const float* __restrict__ bias_exp,
                  float* __restrict__ out){
  __shared__ __align__(16) u16 smem[20480];   // 40 KB
  u16* sLN = smem;
  u16* sQ  = smem;
  u16* sK  = smem + 8192;
  u16* sP  = smem;                    // per-head [64 q][64 k] at wid*4096 u16
  u16* sO  = smem;
  u16* stg = smem + 8192;
  u16* sH  = smem;                    // overlays sO after B8
  u16* sG  = smem + 16384;            // [64 tok][64 hid] bf16 (overlays V)
  u8*  sVe5 = (u8*)(smem + 16384);    // V^T [128 d][64 tok] e5m2, 8KB

  const int tid = threadIdx.x, lane = tid & 63, wid = tid >> 6;
  const int wdw = blockIdx.x;
  const int bb = wdw >> 6, ihb = (wdw >> 3) & 7, iwb = wdw & 7;
  const float* xb = x + (size_t)bb * 4096 * 128;
  float* ob = out + (size_t)bb * 4096 * 128;
  const f32x4 z4 = {0.f, 0.f, 0.f, 0.f};
  const int rb = tid >> 4, cb = tid & 15, c0g = cb * 8;
  const int r15 = lane & 15, kg = lane >> 4;

  // ---- P1: load window + LN1 -> sLN (coalesced: 16 lanes x 8ch per row) ----
  {
    float g8[8], b8[8];
    *(f32x4*)&g8[0] = *(const f32x4*)(ln1_g + c0g);
    *(f32x4*)&g8[4] = *(const f32x4*)(ln1_g + c0g + 4);
    *(f32x4*)&b8[0] = *(const f32x4*)(ln1_b + c0g);
    *(f32x4*)&b8[4] = *(const f32x4*)(ln1_b + c0g + 4);
    #pragma unroll
    for (int it = 0; it < 4; ++it){
      const int r = it * 16 + rb;
      const int pix = ((r >> 3) * 8 + ihb) * 64 + (r & 7) * 8 + iwb;
      float fl[8];
      *(f32x4*)&fl[0] = *(const f32x4*)(xb + (size_t)pix * 128 + c0g);
      *(f32x4*)&fl[4] = *(const f32x4*)(xb + (size_t)pix * 128 + c0g + 4);
      float s = 0.f, sq = 0.f;
      #pragma unroll
      for (int j = 0; j < 8; ++j){ s += fl[j]; sq += fl[j]*fl[j]; }
      #pragma unroll
      for (int m = 1; m < 16; m <<= 1){ s += __shfl_xor(s, m); sq += __shfl_xor(sq, m); }
      const float mean = s * (1.f/128.f);
      const float rs = __builtin_amdgcn_rsqf(sq * (1.f/128.f) - mean*mean + 1e-5f);
      bf16x8 o;
      #pragma unroll
      for (int j = 0; j < 8; ++j) o[j] = fbf((fl[j]-mean)*rs*g8[j] + b8[j]);
      *(bf16x8*)&sLN[r*128 + (c0g ^ ((r & 7) << 3))] = o;
    }
  }
  __syncthreads();   // B1

  // ---- P2: QKV. Q^T,K^T transposed-GEMM; V normal-GEMM. wave = head ----
  {
    f32x4 aqk[4][4];   // [chtile Q0,Q1,K0,K1][token tile]
    f32x4 av[4][2];    // [token tile][d tile]
    #pragma unroll
    for (int ct = 0; ct < 4; ++ct){
      const f32x4 bq = *(const f32x4*)(qkv_b + wid*96 + ct*16 + kg*4);
      #pragma unroll
      for (int tt = 0; tt < 4; ++tt) aqk[ct][tt] = bq;
    }
    #pragma unroll
    for (int nt = 0; nt < 2; ++nt){
      const float bv = qkv_b[wid*96 + 64 + nt*16 + r15];
      const f32x4 bv4 = {bv, bv, bv, bv};
      #pragma unroll
      for (int mt = 0; mt < 4; ++mt) av[mt][nt] = bv4;
    }
    #pragma unroll
    for (int kk = 0; kk < 4; ++kk){
      bf16x8 L[4], aW[4], bWv[2];
      const int c0 = kk*32 + kg*8;
      #pragma unroll
      for (int t = 0; t < 4; ++t){
        const int row = t*16 + r15;
        L[t] = *(const bf16x8*)&sLN[row*128 + (c0 ^ ((row & 7) << 3))];
      }
      #pragma unroll
      for (int ct = 0; ct < 4; ++ct)
        aW[ct] = *(const bf16x8*)(rep_qkv + (size_t)((kk*24 + wid*6 + ct)*64 + lane)*8);
      #pragma unroll
      for (int nt = 0; nt < 2; ++nt)
        bWv[nt] = *(const bf16x8*)(rep_qkv + (size_t)((kk*24 + wid*6 + 4 + nt)*64 + lane)*8);
      #pragma unroll
      for (int ct = 0; ct < 4; ++ct)
        #pragma unroll
        for (int tt = 0; tt < 4; ++tt)
          aqk[ct][tt] = __builtin_amdgcn_mfma_f32_16x16x32_bf16(aW[ct], L[tt], aqk[ct][tt], 0, 0, 0);
      #pragma unroll
      for (int mt = 0; mt < 4; ++mt)
        #pragma unroll
        for (int nt = 0; nt < 2; ++nt)
          av[mt][nt] = __builtin_amdgcn_mfma_f32_16x16x32_bf16(L[mt], bWv[nt], av[mt][nt], 0, 0, 0);
    }
    __syncthreads();   // B2: sLN dead; sQ may overlay
    // Q pre-scaled by 1/sqrt(HD) * log2(e) for exp2 softmax
    #pragma unroll
    for (int ct = 0; ct < 4; ++ct){
      u16* dst = (ct < 2) ? sQ : sK;
      const float scl = (ct < 2) ? 0.2550348296f : 1.0f;
      const int colu = wid*32 + (ct & 1)*16 + kg*4;
      #pragma unroll
      for (int tt = 0; tt < 4; ++tt){
        const int row = tt*16 + r15;
        bf16x4 pk;
        #pragma unroll
        for (int rg = 0; rg < 4; ++rg) pk[rg] = fbf(aqk[ct][tt][rg] * scl);
        *(bf16x4*)&dst[row*128 + (colu ^ ((row & 7) << 3))] = pk;
      }
    }
    // V -> e5m2 V^T [d_all][64 tok] (own-wave 32-row slab)
    #pragma unroll
    for (int nt = 0; nt < 2; ++nt){
      const int row = wid*32 + nt*16 + r15;       // d_all
      #pragma unroll
      for (int mt = 0; mt < 4; ++mt){
        const int colu = mt*16 + kg*4;            // token (byte)
        unsigned pk = f2e5(av[mt][nt][0]) | (f2e5(av[mt][nt][1]) << 8)
                    | (f2e5(av[mt][nt][2]) << 16) | (f2e5(av[mt][nt][3]) << 24);
        *(unsigned*)(sVe5 + row*64 + (colu ^ ((row & 7) << 3))) = pk;
      }
    }
  }
  __syncthreads();   // B3

  // ---- P3: S^T = K·Q^T + bias (C-input), softmax over k (exp2, no-max) ----
  f32x4 s4[4][4];   // [k tile][q tile]
  {
    bf16x8 aK[4], bQ[4];
    #pragma unroll
    for (int t = 0; t < 4; ++t){
      const int row = t*16 + r15;
      const int off = (wid*32 + kg*8) ^ ((row & 7) << 3);
      aK[t] = *(const bf16x8*)&sK[row*128 + off];
      bQ[t] = *(const bf16x8*)&sQ[row*128 + off];
    }
    #pragma unroll
    for (int mtk = 0; mtk < 4; ++mtk)
      #pragma unroll
      for (int ntq = 0; ntq < 4; ++ntq){
        const f32x4 cb4 = *(const f32x4*)(bias_exp + (size_t)(((wid*4 + mtk)*4 + ntq)*64 + lane)*4);
        s4[mtk][ntq] = __builtin_amdgcn_mfma_f32_16x16x32_bf16(aK[mtk], bQ[ntq], cb4, 0, 0, 0);
      }
  }
  #pragma unroll
  for (int ntq = 0; ntq < 4; ++ntq){
    float sum = 0.f;
    #pragma unroll
    for (int mtk = 0; mtk < 4; ++mtk)
      #pragma unroll
      for (int rg = 0; rg < 4; ++rg){
        const float e = __builtin_amdgcn_exp2f(s4[mtk][ntq][rg]);
        s4[mtk][ntq][rg] = e; sum += e;
      }
    sum += __shfl_xor(sum, 16);
    sum += __shfl_xor(sum, 32);
    const float inv = __builtin_amdgcn_rcpf(sum);
    #pragma unroll
    for (int mtk = 0; mtk < 4; ++mtk)
      #pragma unroll
      for (int rg = 0; rg < 4; ++rg) s4[mtk][ntq][rg] *= inv;
  }
  __syncthreads();   // B4: Q/K dead; sP overlays A+B
  #pragma unroll
  for (int ntq = 0; ntq < 4; ++ntq){
    const int row = ntq*16 + r15;                 // q
    #pragma unroll
    for (int mtk = 0; mtk < 4; ++mtk){
      const int colu = mtk*16 + kg*4;             // k local
      bf16x4 pk;
      #pragma unroll
      for (int rg = 0; rg < 4; ++rg) pk[rg] = fbf(s4[mtk][ntq][rg]);
      *(bf16x4*)&sP[wid*4096 + row*64 + (colu ^ ((row & 7) << 3))] = pk;
    }
  }
  // no barrier: P and V fragments below are own-wave regions

  // ---- P4: O^T = V^T·P^T (V unpacked e5m2->bf16) -> sO[tok][ch] ----
  {
    f32x4 o4[2][4];   // [d tile][q tile]
    #pragma unroll
    for (int dt = 0; dt < 2; ++dt)
      #pragma unroll
      for (int qt = 0; qt < 4; ++qt) o4[dt][qt] = z4;
    #pragma unroll
    for (int ks = 0; ks < 2; ++ks){
      bf16x8 aV[2], bP[4];
      #pragma unroll
      for (int dt = 0; dt < 2; ++dt){
        const int rowd = wid*32 + dt*16 + r15;
        const u8* pv = sVe5 + rowd*64 + ((ks*32 + kg*8) ^ ((rowd & 7) << 3));
        const unsigned w0 = *(const unsigned*)pv;
        const unsigned w1 = *(const unsigned*)(pv + 4);
        bf16x8 a;
        #pragma unroll
        for (int j = 0; j < 4; ++j){
          a[j]   = fbf(e52f((w0 >> (8*j)) & 0xFFu));
          a[4+j] = fbf(e52f((w1 >> (8*j)) & 0xFFu));
        }
        aV[dt] = a;
      }
      #pragma unroll
      for (int qt = 0; qt < 4; ++qt){
        const int rowq = qt*16 + r15;
        bP[qt] = *(const bf16x8*)&sP[wid*4096 + rowq*64 + ((ks*32 + kg*8) ^ ((rowq & 7) << 3))];
      }
      #pragma unroll
      for (int dt = 0; dt < 2; ++dt)
        #pragma unroll
        for (int qt = 0; qt < 4; ++qt)
          o4[dt][qt] = __builtin_amdgcn_mfma_f32_16x16x32_bf16(aV[dt], bP[qt], o4[dt][qt], 0, 0, 0);
    }
    __syncthreads();   // B6: P,V dead; sO overlays A
    #pragma unroll
    for (int dt = 0; dt < 2; ++dt){
      const int dbase = wid*32 + dt*16 + kg*4;
      #pragma unroll
      for (int qt = 0; qt < 4; ++qt){
        const int q = qt*16 + r15;
        bf16x4 pk;
        #pragma unroll
        for (int rg = 0; rg < 4; ++rg) pk[rg] = fbf(o4[dt][qt][rg]);
        *(bf16x4*)&sO[q*128 + (dbase ^ ((q & 7) << 3))] = pk;
      }
    }
  }
  __syncthreads();   // B7: O complete

  // ---- P5: proj^T = Wp^T·O^T; msa = x + proj in regs -> stg (bf16, B) ----
  {
    f32x4 xv[2][4];
    #pragma unroll
    for (int ot = 0; ot < 2; ++ot){
      const int cbase = (wid*2 + ot)*16 + kg*4;
      #pragma unroll
      for (int tt = 0; tt < 4; ++tt){
        const int tok = tt*16 + r15;
        const int pix = ((tok >> 3) * 8 + ihb) * 64 + (tok & 7) * 8 + iwb;
        xv[ot][tt] = *(const f32x4*)(xb + (size_t)pix * 128 + cbase);
      }
    }
    f32x4 po[2][4];   // [out-ch tile][token tile]
    #pragma unroll
    for (int ot = 0; ot < 2; ++ot){
      const f32x4 pb4 = *(const f32x4*)(proj_b + (wid*2 + ot)*16 + kg*4);
      #pragma unroll
      for (int tt = 0; tt < 4; ++tt) po[ot][tt] = pb4;
    }
    #pragma unroll
    for (int kk = 0; kk < 4; ++kk){
      bf16x8 aWp[2], bO[4];
      #pragma unroll
      for (int ot = 0; ot < 2; ++ot)
        aWp[ot] = *(const bf16x8*)(rep_proj + (size_t)((kk*8 + wid*2 + ot)*64 + lane)*8);
      #pragma unroll
      for (int tt = 0; tt < 4; ++tt){
        const int row = tt*16 + r15;
        bO[tt] = *(const bf16x8*)&sO[row*128 + ((kk*32 + kg*8) ^ ((row & 7) << 3))];
      }
      #pragma unroll
      for (int ot = 0; ot < 2; ++ot)
        #pragma unroll
        for (int tt = 0; tt < 4; ++tt)
          po[ot][tt] = __builtin_amdgcn_mfma_f32_16x16x32_bf16(aWp[ot], bO[tt], po[ot][tt], 0, 0, 0);
    }
    #pragma unroll
    for (int ot = 0; ot < 2; ++ot){
      const int cbase = (wid*2 + ot)*16 + kg*4;
      #pragma unroll
      for (int tt = 0; tt < 4; ++tt){
        const int tok = tt*16 + r15;
        bf16x4 pk;
        #pragma unroll
        for (int rg = 0; rg < 4; ++rg) pk[rg] = fbf(po[ot][tt][rg] + xv[ot][tt][rg]);
        *(bf16x4*)&stg[tok*128 + (cbase ^ ((tok & 7) << 3))] = pk;
      }
    }
  }
  __syncthreads();   // B8: msa(stg) ready; all sO reads done

  // ---- P6: LN2(stg) -> sH (A, overlays sO) ----
  {
    float g8[8], b8[8];
    *(f32x4*)&g8[0] = *(const f32x4*)(ln2_g + c0g);
    *(f32x4*)&g8[4] = *(const f32x4*)(ln2_g + c0g + 4);
    *(f32x4*)&b8[0] = *(const f32x4*)(ln2_b + c0g);
    *(f32x4*)&b8[4] = *(const f32x4*)(ln2_b + c0g + 4);
    #pragma unroll
    for (int it = 0; it < 4; ++it){
      const int r = it * 16 + rb;
      bf16x8 m8 = *(const bf16x8*)&stg[r*128 + (c0g ^ ((r & 7) << 3))];
      float fl[8];
      #pragma unroll
      for (int j = 0; j < 8; ++j) fl[j] = bf2f(m8[j]);
      float s = 0.f, sq = 0.f;
      #pragma unroll
      for (int j = 0; j < 8; ++j){ s += fl[j]; sq += fl[j]*fl[j]; }
      #pragma unroll
      for (int m = 1; m < 16; m <<= 1){ s += __shfl_xor(s, m); sq += __shfl_xor(sq, m); }
      const float mean = s * (1.f/128.f);
      const float rs = __builtin_amdgcn_rsqf(sq * (1.f/128.f) - mean*mean + 1e-5f);
      bf16x8 o;
      #pragma unroll
      for (int j = 0; j < 8; ++j) o[j] = fbf((fl[j]-mean)*rs*g8[j] + b8[j]);
      *(bf16x8*)&sH[r*128 + (c0g ^ ((r & 7) << 3))] = o;
    }
  }
  __syncthreads();   // B9

  // ---- P7: MLP transposed, 8 chunks of 64 hidden, software-pipelined:
  //      GEMM1(c+1) issues between the sG-ready barrier and GEMM2(c). ----
  f32x4 accO[2][4];   // [out-ch tile][token tile]
  #pragma unroll
  for (int ot = 0; ot < 2; ++ot){
    const f32x4 b2v = *(const f32x4*)(mlp_b2 + (wid*2 + ot)*16 + kg*4);
    #pragma unroll
    for (int tt = 0; tt < 4; ++tt) accO[ot][tt] = b2v;
  }

  f32x4 t4[4];        // pre-activation for the CURRENT chunk (this wave's
                      // hidden 16-group = c*4 + wid)
  // prologue: GEMM1 for chunk 0
  {
    const f32x4 b1v = *(const f32x4*)(mlp_b1 + (0*4 + wid)*16 + kg*4);
    #pragma unroll
    for (int tt = 0; tt < 4; ++tt) t4[tt] = b1v;
    #pragma unroll
    for (int kk = 0; kk < 4; ++kk){
      const int c0 = kk*32 + kg*8;
      bf16x8 aW = *(const bf16x8*)(rep_w1 + (size_t)((kk*32 + 0*4 + wid)*64 + lane)*8);
      #pragma unroll
      for (int tt = 0; tt < 4; ++tt){
        const int row = tt*16 + r15;
        bf16x8 bL = *(const bf16x8*)&sH[row*128 + (c0 ^ ((row & 7) << 3))];
        t4[tt] = __builtin_amdgcn_mfma_f32_16x16x32_bf16(aW, bL, t4[tt], 0, 0, 0);
      }
    }
  }

  #pragma unroll
  for (int c = 0; c < 8; ++c){
    // sigmoid-GELU (exp2 domain) on current chunk
    bf16x4 gp[4];
    #pragma unroll
    for (int tt = 0; tt < 4; ++tt){
      #pragma unroll
      for (int rg = 0; rg < 4; ++rg){
        const float v = t4[tt][rg];
        const float e = __builtin_amdgcn_exp2f(-2.4554669f * v);
        gp[tt][rg] = fbf(v * __builtin_amdgcn_rcpf(1.f + e));
      }
    }
    __syncthreads();   // prior chunk's sG reads complete (c=0: V reads pre-B6)
    {
      const int colu = wid*16 + kg*4;             // hidden local [0,64)
      #pragma unroll
      for (int tt = 0; tt < 4; ++tt){
        const int row = tt*16 + r15;
        *(bf16x4*)&sG[row*64 + (colu ^ ((row & 7) << 3))] = gp[tt];
      }
    }
    __syncthreads();   // sG ready
    // GEMM1 for chunk c+1 (reads only sH; independent of sG)
    if (c < 7){
      const f32x4 b1v = *(const f32x4*)(mlp_b1 + ((c+1)*4 + wid)*16 + kg*4);
      f32x4 n4[4];
      #pragma unroll
      for (int tt = 0; tt < 4; ++tt) n4[tt] = b1v;
      #pragma unroll
      for (int kk = 0; kk < 4; ++kk){
        const int c0 = kk*32 + kg*8;
        bf16x8 aW = *(const bf16x8*)(rep_w1 + (size_t)((kk*32 + (c+1)*4 + wid)*64 + lane)*8);
        #pragma unroll
        for (int tt = 0; tt < 4; ++tt){
          const int row = tt*16 + r15;
          bf16x8 bL = *(const bf16x8*)&sH[row*128 + (c0 ^ ((row & 7) << 3))];
          n4[tt] = __builtin_amdgcn_mfma_f32_16x16x32_bf16(aW, bL, n4[tt], 0, 0, 0);
        }
      }
      #pragma unroll
      for (int tt = 0; tt < 4; ++tt) t4[tt] = n4[tt];
    }
    // GEMM2 for chunk c
    #pragma unroll
    for (int kk2 = 0; kk2 < 2; ++kk2){
      bf16x8 aW2[2], bG[4];
      const int c0 = kk2*32 + kg*8;
      #pragma unroll
      for (int ot = 0; ot < 2; ++ot)
        aW2[ot] = *(const bf16x8*)(rep_w2 + (size_t)(((c*2 + kk2)*8 + wid*2 + ot)*64 + lane)*8);
      #pragma unroll
      for (int tt = 0; tt < 4; ++tt){
        const int row = tt*16 + r15;
        bG[tt] = *(const bf16x8*)&sG[row*64 + (c0 ^ ((row & 7) << 3))];
      }
      #pragma unroll
      for (int ot = 0; ot < 2; ++ot)
        #pragma unroll
        for (int tt = 0; tt < 4; ++tt)
          accO[ot][tt] = __builtin_amdgcn_mfma_f32_16x16x32_bf16(aW2[ot], bG[tt], accO[ot][tt], 0, 0, 0);
    }
  }

  // ---- P8: out = msa(stg bf16) + mlp, scattered to image layout ----
  #pragma unroll
  for (int ot = 0; ot < 2; ++ot){
    const int cbase = (wid*2 + ot)*16 + kg*4;
    #pragma unroll
    for (int tt = 0; tt < 4; ++tt){
      const int tok = tt*16 + r15;
      const int pix = ((tok >> 3) * 8 + ihb) * 64 + (tok & 7) * 8 + iwb;
      bf16x4 m4 = *(const bf16x4*)&stg[tok*128 + (cbase ^ ((tok & 7) << 3))];
      f32x4 o;
      #pragma unroll
      for (int rg = 0; rg < 4; ++rg) o[rg] = bf2f(m4[rg]) + accO[ot][tt][rg];
      *(f32x4*)(ob + (size_t)pix * 128 + cbase) = o;
    }
  }
}

// ---------------------------------------------------------------------------
// ws layout (bytes): rq 0..98304 | rp ..131072 | r1 ..262144 | r2 ..393216 |
// be ..458752.
// ---------------------------------------------------------------------------
extern "C" void kernel_launch(void* const* d_in, const int* in_sizes, int n_in,
                              void* d_out, int out_size, void* d_ws, size_t ws_size,
                              hipStream_t stream){
  (void)in_sizes; (void)n_in; (void)out_size; (void)ws_size;
  const float* x      = (const float*)d_in[0];
  const float* qkv_w  = (const float*)d_in[1];
  const float* qkv_b  = (const float*)d_in[2];
  const float* proj_w = (const float*)d_in[3];
  const float* proj_b = (const float*)d_in[4];
  const float* tbl    = (const float*)d_in[5];
  const float* ln1_g  = (const float*)d_in[6];
  const float* ln1_b  = (const float*)d_in[7];
  const float* ln2_g  = (const float*)d_in[8];
  const float* ln2_b  = (const float*)d_in[9];
  const float* w1     = (const float*)d_in[10];
  const float* b1     = (const float*)d_in[11];
  const float* w2     = (const float*)d_in[12];
  const float* b2     = (const float*)d_in[13];

  char* ws = (char*)d_ws;
  u16*   rq  = (u16*)ws;
  u16*   rp  = (u16*)(ws + 98304);
  u16*   r1  = (u16*)(ws + 131072);
  u16*   r2  = (u16*)(ws + 262144);
  float* be  = (float*)(ws + 393216);

  hipLaunchKernelGGL(repack_kernel, dim3(256), dim3(256), 0, stream,
                     qkv_w, proj_w, w1, w2, tbl, rq, rp, r1, r2, be);
  hipLaunchKernelGGL(block_kernel, dim3(2048), dim3(256), 0, stream,
                     x, qkv_b, proj_b, ln1_g, ln1_b, ln2_g, ln2_b,
                     rq, rp, r1, r2, b1, b2, be, (float*)d_out);
}